// Round 5
// baseline (133.077 us; speedup 1.0000x reference)
//
#include <hip/hip_runtime.h>

#define BS 32
#define NA 512
#define ID 128
#define NH 8
#define HD 64
#define NHD 512   // NH*HD
#define NEG 0.2f
#define NC 32     // scalar chunk count (G=16) for zps/znp
#define CH 16
#define NW2 16    // waves per k2 block (1024 threads), 32 sorted rows each
#define BPAD 136  // B LDS col stride (bf16 elems): 272B -> 2-way bank alias (free)

typedef short bf16x8 __attribute__((ext_vector_type(8)));
typedef float f32x4 __attribute__((ext_vector_type(4)));

__device__ inline unsigned f2bf_bits(float x) {   // RNE f32 -> bf16 bits
  unsigned u = __float_as_uint(x);
  return (u + 0x7FFFu + ((u >> 16) & 1u)) >> 16;
}

// split 8 floats into bf16 hi + bf16 lo fragments (static indices only)
__device__ inline void split8(const float4& x, const float4& y,
                              bf16x8& hi, bf16x8& lo) {
  float f[8] = {x.x, x.y, x.z, x.w, y.x, y.y, y.z, y.w};
  #pragma unroll
  for (int j = 0; j < 8; ++j) {
    unsigned hb = f2bf_bits(f[j]);
    float r = f[j] - __uint_as_float(hb << 16);
    unsigned lb = f2bf_bits(r);
    hi[j] = (short)hb;
    lo[j] = (short)lb;
  }
}

// K1 (MFMA): hp = h @ W via split-bf16 3-pass (hi*hi + hi*lo + lo*hi), fp32
// accumulate. Unchanged from R4 (verified, ~7us). Writes into io (d_out).
__global__ __launch_bounds__(256, 4) void k1_mfma(
    const float* __restrict__ h, const float* __restrict__ W,
    float* __restrict__ io) {
  __shared__ unsigned short Bhi[64 * BPAD];
  __shared__ unsigned short Blo[64 * BPAD];

  int blk = blockIdx.x;
  int mt = blk >> 3;            // M-tile 0..127 (128 rows each)
  int n0 = (blk & 7) * 64;      // N-tile start col
  int m0 = mt * 128;
  int b = mt >> 2;              // batch
  int nbase = (mt & 3) * 128;   // agent-row base within batch
  int head = n0 >> 6;
  int t = threadIdx.x;
  int lane = t & 63, w = t >> 6;
  int q = lane >> 4, ml = lane & 15;

  // ---- stage W[n0..n0+63] split+transposed into LDS ----
  {
    int c = t & 63, kq = t >> 6;
    const float* wsrc = W + (size_t)kq * 32 * NHD + n0 + c;
    #pragma unroll 4
    for (int kk = 0; kk < 32; ++kk) {
      int k = kq * 32 + kk;
      float x = wsrc[(size_t)kk * NHD];
      unsigned hb = f2bf_bits(x);
      float r = x - __uint_as_float(hb << 16);
      Bhi[c * BPAD + k] = (unsigned short)hb;
      Blo[c * BPAD + k] = (unsigned short)f2bf_bits(r);
    }
  }
  __syncthreads();

  f32x4 acc[2][4];
  #pragma unroll
  for (int mf = 0; mf < 2; ++mf)
    #pragma unroll
    for (int nf = 0; nf < 4; ++nf)
      acc[mf][nf] = (f32x4){0.f, 0.f, 0.f, 0.f};

  const float* A0 = h + (size_t)(m0 + w * 32 + ml) * ID;

  #pragma unroll
  for (int ks = 0; ks < 4; ++ks) {
    int ko = ks * 32 + q * 8;          // my k mapping: k = 8*quarter + elem
    bf16x8 ah[2], al[2];
    #pragma unroll
    for (int mf = 0; mf < 2; ++mf) {
      const float* ap = A0 + mf * 16 * ID + ko;
      float4 f0 = *(const float4*)ap;
      float4 f1 = *(const float4*)(ap + 4);
      split8(f0, f1, ah[mf], al[mf]);
    }
    #pragma unroll
    for (int nf = 0; nf < 4; ++nf) {
      int bo = (nf * 16 + ml) * BPAD + ko;   // same k mapping on B side
      bf16x8 bh = *(const bf16x8*)&Bhi[bo];
      bf16x8 bl = *(const bf16x8*)&Blo[bo];
      #pragma unroll
      for (int mf = 0; mf < 2; ++mf) {
        acc[mf][nf] = __builtin_amdgcn_mfma_f32_16x16x32_bf16(ah[mf], bh, acc[mf][nf], 0, 0, 0);
        acc[mf][nf] = __builtin_amdgcn_mfma_f32_16x16x32_bf16(ah[mf], bl, acc[mf][nf], 0, 0, 0);
        acc[mf][nf] = __builtin_amdgcn_mfma_f32_16x16x32_bf16(al[mf], bh, acc[mf][nf], 0, 0, 0);
      }
    }
  }

  // ---- epilogue: D layout col=lane&15, row=4*(lane>>4)+reg (HW-verified) ----
  {
    float* ob = io + (((size_t)b * NH + head) * NA + nbase + w * 32) * HD + ml;
    #pragma unroll
    for (int mf = 0; mf < 2; ++mf)
      #pragma unroll
      for (int nf = 0; nf < 4; ++nf)
        #pragma unroll
        for (int r = 0; r < 4; ++r)
          ob[(size_t)(mf * 16 + q * 4 + r) * HD + nf * 16] = acc[mf][nf][r];
  }
}

// K2 (in-place, 1024 threads = 16 waves x 32 sorted rows): io holds hp on
// entry, final output on exit. Same verified math as R3; geometry widened to
// 16 waves/CU (R2's verified 32-row phase structure) to hide phase-A/sweep
// latency. Sort/table phases guarded t<NA; barriers outside guards.
__global__ __launch_bounds__(1024) void k2_fused(
    const float* __restrict__ att, float* __restrict__ io) {
  __shared__ float tv[NA]; __shared__ int tpm[NA];
  __shared__ float sv[NA]; __shared__ int spm[NA];
  __shared__ float wp[NA]; __shared__ float wn[NA];
  __shared__ float sufPc[(NW2 + 1) * 64]; __shared__ float preNc[(NW2 + 1) * 64];
  __shared__ float zps[NA + 1]; __shared__ float znp[NA + 1];
  __shared__ float szP[NC]; __shared__ float szN[NC];
  __shared__ float sufZ[NC + 1]; __shared__ float preZ[NC + 1];
  __shared__ int jsr[NA];      // js per s-rank (non-increasing)
  __shared__ int Earr[NA];     // E[j] = first rank with js <= j
  __shared__ float asrc[HD]; __shared__ float adst[HD];

  int bh = blockIdx.x;
  int head = bh & (NH - 1);
  int t = threadIdx.x;
  int lane = t & 63, w = t >> 6;
  float* vbase = io + (size_t)bh * NA * HD;

  if (t < 2 * HD) {
    float a = att[head * 2 * HD + t];
    if (t < HD) asrc[t] = a; else adst[t - HD] = a;
  }
  __syncthreads();

  // ---- s,t row-dots: thread t = natural row t (float4 loads, L3-hot) ----
  float vt = 0.f, vs = 0.f; int it = t, is_ = t;
  if (t < NA) {
    const float4* vr = (const float4*)(vbase + (size_t)t * HD);
    float s0 = 0.f, s1 = 0.f, t0 = 0.f, t1 = 0.f;
    #pragma unroll
    for (int j = 0; j < HD / 4; j += 2) {
      float4 v0 = vr[j], v1 = vr[j + 1];
      s0 += v0.x*asrc[4*j+0] + v0.y*asrc[4*j+1] + v0.z*asrc[4*j+2] + v0.w*asrc[4*j+3];
      t0 += v0.x*adst[4*j+0] + v0.y*adst[4*j+1] + v0.z*adst[4*j+2] + v0.w*adst[4*j+3];
      s1 += v1.x*asrc[4*j+4] + v1.y*asrc[4*j+5] + v1.z*asrc[4*j+6] + v1.w*asrc[4*j+7];
      t1 += v1.x*adst[4*j+4] + v1.y*adst[4*j+5] + v1.z*adst[4*j+6] + v1.w*adst[4*j+7];
    }
    vs = s0 + s1; vt = t0 + t1;
  }

  // ---- dual hybrid bitonic sort (threads < NA active) ----
  for (int size = 2; size <= NA; size <<= 1) {
    bool dirAsc = ((t & size) == 0);
    for (int stride = size >> 1; stride > 0; stride >>= 1) {
      if (stride >= 64) {
        if (t < NA) {
          tv[t] = vt; tpm[t] = it; sv[t] = vs; spm[t] = is_;
        }
        __syncthreads();
        if (t < NA) {
          float pt = tv[t ^ stride]; int pit = tpm[t ^ stride];
          float ps = sv[t ^ stride]; int pis = spm[t ^ stride];
          bool mn = (((t & stride) == 0) == dirAsc);
          if (mn ? (pt < vt) : (pt > vt)) { vt = pt; it = pit; }
          if (mn ? (ps < vs) : (ps > vs)) { vs = ps; is_ = pis; }
        }
        __syncthreads();
      } else if (t < NA) {
        float pt = __shfl_xor(vt, stride, 64); int pit = __shfl_xor(it, stride, 64);
        float ps = __shfl_xor(vs, stride, 64); int pis = __shfl_xor(is_, stride, 64);
        bool mn = (((t & stride) == 0) == dirAsc);
        if (mn ? (pt < vt) : (pt > vt)) { vt = pt; it = pit; }
        if (mn ? (ps < vs) : (ps > vs)) { vs = ps; is_ = pis; }
      }
    }
  }
  if (t < NA) {
    tv[t] = vt; tpm[t] = it; sv[t] = vs; spm[t] = is_;
  }
  __syncthreads();

  float cmax = fmaxf(tv[NA - 1], 0.f);
  float amax = fmaxf(sv[NA - 1], 0.f);
  if (t < NA) {
    wp[t] = __expf(vt - cmax);
    wn[t] = __expf(NEG * vt - cmax);
  }
  __syncthreads();

  // ---- phase A: wave w reads its 32 sorted V rows once, weighted sums ----
  float vreg[32];
  {
    float aP = 0.f, aN = 0.f;
    #pragma unroll
    for (int jj = 0; jj < 32; ++jj) {
      int j = (w << 5) + jj;
      float vv = vbase[(size_t)tpm[j] * HD + lane];
      vreg[jj] = vv;
      aP += wp[j] * vv;
      aN += wn[j] * vv;
    }
    sufPc[w * 64 + lane] = aP;   // raw; converted in place below
    preNc[w * 64 + lane] = aN;
  }
  __syncthreads();

  // ---- in-place cross-wave scans + scalar chunk sums ----
  if (t < 64) {
    float run = 0.f;
    sufPc[NW2 * 64 + t] = 0.f;
    for (int ww = NW2 - 1; ww >= 0; --ww) {
      run += sufPc[ww * 64 + t];
      sufPc[ww * 64 + t] = run;
    }
  } else if (t < 128) {
    int d = t - 64; float run = 0.f;
    for (int ww = 0; ww < NW2; ++ww) {
      float raw = preNc[ww * 64 + d];
      preNc[ww * 64 + d] = run;
      run += raw;
    }
    preNc[NW2 * 64 + d] = run;
  } else if (t < 160) {
    int c = t - 128; float a = 0.f;
    for (int j = c * CH; j < c * CH + CH; ++j) a += wp[j];
    szP[c] = a;
  } else if (t < 192) {
    int c = t - 160; float a = 0.f;
    for (int j = c * CH; j < c * CH + CH; ++j) a += wn[j];
    szN[c] = a;
  }
  __syncthreads();

  if (t == 0) {
    float run = 0.f; sufZ[NC] = 0.f;
    for (int cc = NC - 1; cc >= 0; --cc) { run += szP[cc]; sufZ[cc] = run; }
  } else if (t == 1) {
    float run = 0.f;
    for (int cc = 0; cc <= NC; ++cc) { preZ[cc] = run; if (cc < NC) run += szN[cc]; }
  }
  __syncthreads();

  // ---- full-resolution scalar denominator tables + per-rank js ----
  if (t < NA) {
    int ch = t >> 4;
    float a = 0.f;
    for (int k = t; k < ch * CH + CH; ++k) a += wp[k];
    zps[t] = a + sufZ[ch + 1];
    float b2 = 0.f;
    for (int k = ch * CH; k < t; ++k) b2 += wn[k];
    znp[t] = preZ[ch] + b2;
    if (t == 0) { zps[NA] = 0.f; znp[NA] = preZ[NC]; }
    // js for s-rank t (vs in reg): first sorted-t position with tv >= -vs
    float key = -vs;
    int lo = 0, hi = NA;
    while (lo < hi) { int mid = (lo + hi) >> 1; if (tv[mid] < key) lo = mid + 1; else hi = mid; }
    jsr[t] = lo;
  }
  __syncthreads();

  // ---- E[j]: first rank with jsr <= j (jsr sorted descending) ----
  if (t < NA) {
    int lo = 0, hi = NA;
    while (lo < hi) { int mid = (lo + hi) >> 1; if (jsr[mid] > t) lo = mid + 1; else hi = mid; }
    Earr[t] = lo;
  }
  __syncthreads();

  // ---- ascending sweep with inline emission (writes io in place) ----
  {
    float sufPv = sufPc[w * 64 + lane];      // suffix incl. this wave's rows
    float preSeedN = preNc[w * 64 + lane];   // exact prefix before this wave
    float runN = 0.f;
    size_t obase = (size_t)bh * NA * HD + lane;
    int eprev = (w == 0) ? NA : Earr[(w << 5) - 1];   // E[j-1] carried
    #pragma unroll 1
    for (int jj = 0; jj < 32; ++jj) {
      int j = (w << 5) + jj;
      int ecur = Earr[j];
      float preNv = preSeedN + runN;
      for (int r = ecur; r < eprev; ++r) {   // ranks with js == j
        float s = sv[r];
        float A = __expf(s - amax);
        float B = __expf(NEG * s - amax);
        float inv = 1.f / (A * zps[j] + B * znp[j]);
        float x = (A * sufPv + B * preNv) * inv;
        int orow = spm[r];
        io[obase + (size_t)orow * HD] = x > 0.f ? x : __expf(x) - 1.f;
      }
      float vv = vreg[jj];
      sufPv -= wp[j] * vv;
      runN  += wn[j] * vv;
      eprev = ecur;
    }
    if (w == NW2 - 1) {                      // group js == 512: ranks [0, E[511])
      float preNv = preSeedN + runN;         // == total N prefix
      for (int r = 0; r < eprev; ++r) {
        float s = sv[r];
        float A = __expf(s - amax);
        float B = __expf(NEG * s - amax);
        float inv = 1.f / (A * zps[NA] + B * znp[NA]);  // zps[NA]==0
        float x = (B * preNv) * inv;
        int orow = spm[r];
        io[obase + (size_t)orow * HD] = x > 0.f ? x : __expf(x) - 1.f;
      }
    }
  }
}

extern "C" void kernel_launch(void* const* d_in, const int* in_sizes, int n_in,
                              void* d_out, int out_size, void* d_ws, size_t ws_size,
                              hipStream_t stream) {
  const float* h   = (const float*)d_in[0];
  const float* W   = (const float*)d_in[1];
  const float* att = (const float*)d_in[2];
  float* io = (float*)d_out;
  (void)d_ws; (void)ws_size;

  k1_mfma <<<dim3(1024),    dim3(256),  0, stream>>>(h, W, io);
  k2_fused<<<dim3(BS * NH), dim3(1024), 0, stream>>>(att, io);
}